// Round 1
// baseline (1909.089 us; speedup 1.0000x reference)
//
#include <hip/hip_runtime.h>

// LogEig of 32768 SPD 32x32 fp32 matrices.
// One-sided Jacobi SVD on W (init W=P): rotations orthogonalize column pairs.
// For SPD, singular values = eigenvalues and U = normalized converged columns.
// Layout: 1 block = 1 wave (64 lanes) = 2 matrices; lane owns one 32-elem column
// in registers. Partner columns exchanged via __shfl (ds_bpermute).

#define SWEEPS 10

__global__ __launch_bounds__(64) void logeig_kernel(const float* __restrict__ P,
                                                    float* __restrict__ out,
                                                    int nmat) {
    const int lane = threadIdx.x;     // 0..63
    const int half = lane >> 5;       // which of the 2 matrices in this wave
    const int c    = lane & 31;       // column index owned by this lane
    int mat = blockIdx.x * 2 + half;
    if (mat >= nmat) mat = nmat - 1;  // clamp (benign duplicate for odd tails)

    // Load column c. P is symmetric, so column c == row c (contiguous, float4).
    float w[32];
    {
        const float4* src4 =
            reinterpret_cast<const float4*>(P + (size_t)mat * 1024 + (size_t)c * 32);
        #pragma unroll
        for (int k = 0; k < 8; ++k) {
            float4 v = src4[k];
            w[4*k+0] = v.x; w[4*k+1] = v.y; w[4*k+2] = v.z; w[4*k+3] = v.w;
        }
    }

    // ---- one-sided Jacobi sweeps (cyclic, round-robin tournament order) ----
    #pragma unroll 1
    for (int sweep = 0; sweep < SWEEPS; ++sweep) {
        #pragma unroll 1
        for (int r = 0; r < 31; ++r) {
            // Tournament pairing: players 0..30 + fixed 31.
            // round r: (r,31) paired; else i pairs with (2r - i) mod 31.
            int m = 2 * r - c;
            m = (m < 0)   ? m + 31 : m;
            m = (m >= 31) ? m - 31 : m;
            int o = m;
            if (c == r)  o = 31;
            if (c == 31) o = r;
            const int srcLane = (lane & 32) | o;

            // Fetch partner column; fused Gram dot + own norm.
            float other[32];
            float dot = 0.f, nrm = 0.f;
            #pragma unroll
            for (int k = 0; k < 32; ++k) {
                other[k] = __shfl(w[k], srcLane, 64);
                dot = fmaf(w[k], other[k], dot);
                nrm = fmaf(w[k], w[k], nrm);
            }
            const float onrm = __shfl(nrm, srcLane, 64);
            const bool is_p = (c < o);
            const float gpp = is_p ? nrm : onrm;
            const float gqq = is_p ? onrm : nrm;

            // Jacobi rotation zeroing Gram(p,q): t^2 + 2*tau*t - 1 = 0, small root.
            // Both lanes of a pair compute bitwise-identical dot/gpp/gqq => same (cr,sr).
            const float tau = (gqq - gpp) * 0.5f * __builtin_amdgcn_rcpf(dot);
            const float at  = fabsf(tau);
            float t = __builtin_amdgcn_rcpf(at + __builtin_amdgcn_sqrtf(fmaf(at, at, 1.f)));
            t = copysignf(t, tau);
            if (fabsf(dot) < 1e-37f) t = 0.f;  // skip (also kills 0/0 NaN)
            const float cr = __builtin_amdgcn_rsqf(fmaf(t, t, 1.f));
            const float sr = t * cr;
            // p-side: w' = cr*w - sr*other ; q-side: w' = cr*w + sr*other
            const float se = is_p ? -sr : sr;
            #pragma unroll
            for (int k = 0; k < 32; ++k) {
                w[k] = fmaf(cr, w[k], se * other[k]);
            }
        }
    }

    // ---- epilogue: sigma, log, normalize, X = sum_c l_c * u_c u_c^T ----
    float nrm2 = 0.f;
    #pragma unroll
    for (int k = 0; k < 32; ++k) nrm2 = fmaf(w[k], w[k], nrm2);
    const float inv = __builtin_amdgcn_rsqf(nrm2);            // 1/sigma
    const float lg  = 0.34657359f * __builtin_amdgcn_logf(nrm2); // 0.5*ln(nrm2)=ln(sigma)

    // LDS stride 36: strided per-lane reads hit banks (4c+i)%32 (conflict-free),
    // row base 144B (16B aligned) for broadcast float4 reads.
    __shared__ __align__(16) float S[2][32][36];
    __shared__ float L[2][32];
    #pragma unroll
    for (int k = 0; k < 32; ++k) S[half][c][k] = w[k] * inv;
    L[half][c] = lg;
    __syncthreads();

    // Lane computes row i of X (X symmetric): X[i][j] = sum_cc l*u[i]*u[j].
    const int i = c;
    float acc[32];
    #pragma unroll
    for (int j = 0; j < 32; ++j) acc[j] = 0.f;
    #pragma unroll 4
    for (int cc = 0; cc < 32; ++cc) {
        const float si = S[half][cc][i];
        const float mm = si * L[half][cc];
        const float4* row4 = reinterpret_cast<const float4*>(&S[half][cc][0]);
        #pragma unroll
        for (int j4 = 0; j4 < 8; ++j4) {
            float4 v = row4[j4];
            acc[4*j4+0] = fmaf(mm, v.x, acc[4*j4+0]);
            acc[4*j4+1] = fmaf(mm, v.y, acc[4*j4+1]);
            acc[4*j4+2] = fmaf(mm, v.z, acc[4*j4+2]);
            acc[4*j4+3] = fmaf(mm, v.w, acc[4*j4+3]);
        }
    }

    float4* dst4 = reinterpret_cast<float4*>(out + (size_t)mat * 1024 + (size_t)i * 32);
    #pragma unroll
    for (int j4 = 0; j4 < 8; ++j4) {
        dst4[j4] = make_float4(acc[4*j4+0], acc[4*j4+1], acc[4*j4+2], acc[4*j4+3]);
    }
}

extern "C" void kernel_launch(void* const* d_in, const int* in_sizes, int n_in,
                              void* d_out, int out_size, void* d_ws, size_t ws_size,
                              hipStream_t stream) {
    const float* P = (const float*)d_in[0];
    float* out = (float*)d_out;
    const int nmat = in_sizes[0] / 1024;          // 32768
    const int nblocks = (nmat + 1) / 2;           // 2 matrices per 64-thread block
    logeig_kernel<<<nblocks, 64, 0, stream>>>(P, out, nmat);
}

// Round 3
// 1889.201 us; speedup vs baseline: 1.0105x; 1.0105x over previous
//
#include <hip/hip_runtime.h>

// LogEig of 32768 SPD 32x32 fp32 matrices via one-sided Jacobi.
// 1 block = 1 wave = 2 matrices; lane owns one column (16 x float2 in VGPRs).
// Round-robin tournament pairing (round 1's proven ordering). Column norms
// recomputed FRESH every round, fused with the dot loop — carrying them via
// Rutishauser updates (round 2) destroyed relative accuracy of small
// eigenvalues (cancellation: gpp' = gpp - dot^2/(gqq-gpp)) and failed.
// __launch_bounds__(64,4): 128-VGPR budget; round 1's default budget (56
// VGPRs) spilled the column arrays to scratch (VALUBusy capped at 62%).

typedef float v2f __attribute__((ext_vector_type(2)));

#define SWEEPS 10

static __device__ __forceinline__ float bperm(int addr, float v) {
    return __builtin_bit_cast(float,
        __builtin_amdgcn_ds_bpermute(addr, __builtin_bit_cast(int, v)));
}

__global__ __launch_bounds__(64, 4) void logeig_kernel(const float* __restrict__ P,
                                                       float* __restrict__ out,
                                                       int nmat) {
    const int lane = threadIdx.x;     // 0..63
    const int half = lane >> 5;       // which matrix in this wave
    const int c    = lane & 31;       // owned column index
    int mat = blockIdx.x * 2 + half;
    if (mat >= nmat) mat = nmat - 1;

    // Load column c (P symmetric -> column c == row c, contiguous).
    v2f w2[16];
    {
        const float4* src4 =
            reinterpret_cast<const float4*>(P + (size_t)mat * 1024 + (size_t)c * 32);
        #pragma unroll
        for (int k = 0; k < 8; ++k) {
            float4 v = src4[k];
            w2[2*k]   = (v2f){v.x, v.y};
            w2[2*k+1] = (v2f){v.z, v.w};
        }
    }

    const int laneb = lane << 2;

    #pragma unroll 1
    for (int sweep = 0; sweep < SWEEPS; ++sweep) {
        #pragma unroll 1
        for (int r = 0; r < 31; ++r) {
            // Tournament pairing: players 0..30 rotate, 31 fixed.
            // round r: (r,31) paired; else i pairs with (2r - i) mod 31.
            int m = 2 * r - c;
            m = (m < 0)   ? m + 31 : m;
            m = (m >= 31) ? m - 31 : m;
            int o = m;
            if (c == r)  o = 31;
            if (c == 31) o = r;
            const int addr = laneb ^ ((c ^ o) << 2);  // partner byte-address (same half)

            // Fetch partner column; fused dot (w.o) + fresh own norm (w.w).
            v2f o2[16];
            v2f dA = {0.f, 0.f}, dB = {0.f, 0.f};
            v2f nA = {0.f, 0.f}, nB = {0.f, 0.f};
            #pragma unroll
            for (int k = 0; k < 16; ++k) {
                v2f ov;
                ov[0] = bperm(addr, w2[k][0]);
                ov[1] = bperm(addr, w2[k][1]);
                o2[k] = ov;
                if (k & 1) { dB += w2[k] * ov; nB += w2[k] * w2[k]; }
                else       { dA += w2[k] * ov; nA += w2[k] * w2[k]; }
            }
            v2f dT = dA + dB, nT = nA + nB;
            const float dot = dT[0] + dT[1];   // bitwise-identical across the pair
            const float nrm = nT[0] + nT[1];
            const float onrm = bperm(addr, nrm);

            const bool is_p = (c < o);
            const float gpp = is_p ? nrm : onrm;
            const float gqq = is_p ? onrm : nrm;

            // Jacobi rotation zeroing Gram(p,q); small-root t of t^2+2*tau*t-1=0.
            const float tau = (gqq - gpp) * 0.5f * __builtin_amdgcn_rcpf(dot);
            const float at  = fabsf(tau);
            float t = __builtin_amdgcn_rcpf(at + __builtin_amdgcn_sqrtf(fmaf(at, at, 1.f)));
            t = copysignf(t, tau);
            if (fabsf(dot) < 1e-37f) t = 0.f;   // skip / kill 0/0 NaN
            const float cr = __builtin_amdgcn_rsqf(fmaf(t, t, 1.f));
            const float sr = t * cr;
            const float se = is_p ? -sr : sr;   // p: w' = c*w - s*o ; q: w' = c*w + s*o

            #pragma unroll
            for (int k = 0; k < 16; ++k)
                w2[k] = cr * w2[k] + se * o2[k];   // v_pk_mul + v_pk_fma
        }
    }

    // ---- epilogue: sigma, log, normalize, X = sum_c l_c * u_c u_c^T ----
    float nrm2;
    {
        v2f nA = w2[0] * w2[0], nB = w2[1] * w2[1];
        #pragma unroll
        for (int k = 2; k < 16; k += 2) {
            nA += w2[k] * w2[k];
            nB += w2[k + 1] * w2[k + 1];
        }
        v2f nT = nA + nB;
        nrm2 = nT[0] + nT[1];
    }
    const float inv = __builtin_amdgcn_rsqf(nrm2);               // 1/sigma
    const float lg  = 0.34657359f * __builtin_amdgcn_logf(nrm2); // ln(sigma) = (ln2/2)*log2

    // LDS stride 36: per-lane strided reads conflict-free, rows 16B-aligned.
    __shared__ __align__(16) float S[2][32][36];
    __shared__ float L[2][32];
    #pragma unroll
    for (int k = 0; k < 16; ++k) {
        S[half][c][2*k]   = w2[k][0] * inv;
        S[half][c][2*k+1] = w2[k][1] * inv;
    }
    L[half][c] = lg;
    __syncthreads();

    // Lane computes row i of X: X[i][j] = sum_cc l*u[i]*u[j].
    const int i = c;
    v2f acc[16];
    #pragma unroll
    for (int j = 0; j < 16; ++j) acc[j] = (v2f){0.f, 0.f};
    #pragma unroll 4
    for (int cc = 0; cc < 32; ++cc) {
        const float si = S[half][cc][i];
        const float mm = si * L[half][cc];
        const float4* row4 = reinterpret_cast<const float4*>(&S[half][cc][0]);
        #pragma unroll
        for (int j4 = 0; j4 < 8; ++j4) {
            float4 v = row4[j4];
            acc[2*j4]   += mm * (v2f){v.x, v.y};
            acc[2*j4+1] += mm * (v2f){v.z, v.w};
        }
    }

    float4* dst4 = reinterpret_cast<float4*>(out + (size_t)mat * 1024 + (size_t)i * 32);
    #pragma unroll
    for (int j4 = 0; j4 < 8; ++j4) {
        dst4[j4] = make_float4(acc[2*j4][0], acc[2*j4][1], acc[2*j4+1][0], acc[2*j4+1][1]);
    }
}

extern "C" void kernel_launch(void* const* d_in, const int* in_sizes, int n_in,
                              void* d_out, int out_size, void* d_ws, size_t ws_size,
                              hipStream_t stream) {
    const float* P = (const float*)d_in[0];
    float* out = (float*)d_out;
    const int nmat = in_sizes[0] / 1024;     // 32768
    const int nblocks = (nmat + 1) / 2;      // 2 matrices per 64-thread block
    logeig_kernel<<<nblocks, 64, 0, stream>>>(P, out, nmat);
}